// Round 3
// baseline (2627.594 us; speedup 1.0000x reference)
//
#include <hip/hip_runtime.h>

#define D 128
#define TE 16
#define TPE 8            // threads per row in GN reduction (128 threads / 16 rows)
#define EPS 1e-5f

// Per-row mean/rstd of buf[TE][D] into red_m/red_r. All 128 threads participate.
__device__ __forceinline__ void gn_reduce(const float* buf, float* red_m, float* red_r, int j)
{
    int e = j / TPE;          // row this thread helps reduce
    int t = j % TPE;          // lane within the row's 8-lane reduction group
    float s = 0.f, s2 = 0.f;
#pragma unroll
    for (int q = 0; q < D / TPE; ++q) {
        float v = buf[e * D + t * (D / TPE) + q];
        s += v; s2 += v * v;
    }
#pragma unroll
    for (int m = TPE / 2; m > 0; m >>= 1) {
        s  += __shfl_xor(s, m);
        s2 += __shfl_xor(s2, m);
    }
    if (t == 0) {
        float mean = s * (1.f / D);
        float var  = s2 * (1.f / D) - mean * mean;
        red_m[e] = mean;
        red_r[e] = rsqrtf(fmaxf(var, 0.f) + EPS);
    }
}

// acc[e] += in[e][:] . Wrow[:]   (in: LDS [TE][D], broadcast reads; Wrow: global, L2)
__device__ __forceinline__ void mm_acc(const float* in, const float* __restrict__ Wrow,
                                       float acc[TE])
{
    const float4* W4 = reinterpret_cast<const float4*>(Wrow);
    for (int k4 = 0; k4 < D / 4; ++k4) {
        float4 w = W4[k4];
#pragma unroll
        for (int e = 0; e < TE; ++e) {
            float4 x = *reinterpret_cast<const float4*>(&in[e * D + 4 * k4]);
            acc[e] = fmaf(w.x, x.x, fmaf(w.y, x.y, fmaf(w.z, x.z, fmaf(w.w, x.w, acc[e]))));
        }
    }
}

// out = relu( GN( in @ W.T ) )   in/out: LDS [TE][D] (must NOT alias)
__device__ __forceinline__ void mm_gn(const float* in, const float* __restrict__ W,
                                      const float* __restrict__ g, const float* __restrict__ b,
                                      float* out, float* red_m, float* red_r, int j)
{
    float acc[TE];
#pragma unroll
    for (int e = 0; e < TE; ++e) acc[e] = 0.f;
    mm_acc(in, W + (size_t)j * D, acc);
#pragma unroll
    for (int e = 0; e < TE; ++e) out[e * D + j] = acc[e];
    __syncthreads();
    gn_reduce(out, red_m, red_r, j);
    __syncthreads();
    float gj = g[j], bj = b[j];
#pragma unroll
    for (int e = 0; e < TE; ++e)
        out[e * D + j] = fmaxf(fmaf((acc[e] - red_m[e]) * red_r[e], gj, bj), 0.f);
    __syncthreads();
}

__global__ __launch_bounds__(256) void zero_kernel(float4* __restrict__ p, int n4)
{
    int i = blockIdx.x * 256 + threadIdx.x;
    int stride = gridDim.x * 256;
    for (; i < n4; i += stride)
        p[i] = make_float4(0.f, 0.f, 0.f, 0.f);
}

// Edge pipeline. c_acc must be pre-zeroed; scatter-adds ctx_w2 output into it.
// LDS = 2*8KB + eps => ~16.6KB.
__global__ __launch_bounds__(128) void edge_kernel(
    const float* __restrict__ agts, const float* __restrict__ ctx,
    const float* __restrict__ agt_ctrs, const float* __restrict__ ctx_ctrs,
    const float* __restrict__ dist_w1, const float* __restrict__ dist_b1,
    const float* __restrict__ dist_w2, const float* __restrict__ dist_g, const float* __restrict__ dist_beta,
    const float* __restrict__ q_w, const float* __restrict__ q_g, const float* __restrict__ q_beta,
    const float* __restrict__ ctx_w1, const float* __restrict__ ctx_g, const float* __restrict__ ctx_beta,
    const float* __restrict__ ctx_w2,
    const int* __restrict__ hi, const int* __restrict__ wi,
    float* __restrict__ c_acc, int E)
{
    __shared__ float bufA[TE][D];
    __shared__ float bufB[TE][D];
    __shared__ float red_m[TE], red_r[TE];
    __shared__ int   s_hi[TE], s_wi[TE];
    __shared__ float s_dx[TE], s_dy[TE];

    const int j  = threadIdx.x;
    const int e0 = blockIdx.x * TE;

    if (j < TE) {
        int ec = min(e0 + j, E - 1);          // tail: clamp (stores are guarded)
        int h = hi[ec], w = wi[ec];
        s_hi[j] = h; s_wi[j] = w;
        s_dx[j] = agt_ctrs[2 * h]     - ctx_ctrs[2 * w];
        s_dy[j] = agt_ctrs[2 * h + 1] - ctx_ctrs[2 * w + 1];
    }
    __syncthreads();

    // P2: bufA = relu(d2 @ dist_w1.T + dist_b1)
    {
        float w0 = dist_w1[2 * j], w1 = dist_w1[2 * j + 1], bb = dist_b1[j];
#pragma unroll
        for (int e = 0; e < TE; ++e)
            bufA[e][j] = fmaxf(fmaf(s_dx[e], w0, fmaf(s_dy[e], w1, bb)), 0.f);
    }
    __syncthreads();

    // P3: bufB = relu(GN(bufA @ dist_w2.T))        [d-branch]
    mm_gn(&bufA[0][0], dist_w2, dist_g, dist_beta, &bufB[0][0], red_m, red_r, j);

    // P4: acc6 += bufB @ ctx_w1.T (K-chunk 0)
    float acc6[TE];
#pragma unroll
    for (int e = 0; e < TE; ++e) acc6[e] = 0.f;
    mm_acc(&bufB[0][0], ctx_w1 + (size_t)j * (3 * D), acc6);

    // P5: bufA = agts[hi] rows
#pragma unroll
    for (int e = 0; e < TE; ++e) bufA[e][j] = agts[(size_t)s_hi[e] * D + j];
    __syncthreads();   // also orders P4's bufB reads before P6's bufB writes

    // P6: bufB = relu(GN(bufA @ q_w.T))            [q-branch]
    mm_gn(&bufA[0][0], q_w, q_g, q_beta, &bufB[0][0], red_m, red_r, j);

    // P7: acc6 += bufB @ ctx_w1.T (K-chunk 1)
    mm_acc(&bufB[0][0], ctx_w1 + (size_t)j * (3 * D) + D, acc6);
    __syncthreads();   // all bufB reads done before overwrite

    // P8: bufB = ctx[wi] rows
#pragma unroll
    for (int e = 0; e < TE; ++e) bufB[e][j] = ctx[(size_t)s_wi[e] * D + j];
    __syncthreads();

    // P9: acc6 += bufB @ ctx_w1.T (K-chunk 2)
    mm_acc(&bufB[0][0], ctx_w1 + (size_t)j * (3 * D) + 2 * D, acc6);

    // P10: bufA = relu(GN(acc6))
#pragma unroll
    for (int e = 0; e < TE; ++e) bufA[e][j] = acc6[e];
    __syncthreads();
    gn_reduce(&bufA[0][0], red_m, red_r, j);
    __syncthreads();
    {
        float gj = ctx_g[j], bj = ctx_beta[j];
#pragma unroll
        for (int e = 0; e < TE; ++e)
            bufA[e][j] = fmaxf(fmaf((acc6[e] - red_m[e]) * red_r[e], gj, bj), 0.f);
    }
    __syncthreads();

    // P11: acc7 = bufA @ ctx_w2.T ; run-merged scatter-add (hi sorted)
    float acc7[TE];
#pragma unroll
    for (int e = 0; e < TE; ++e) acc7[e] = 0.f;
    mm_acc(&bufA[0][0], ctx_w2 + (size_t)j * D, acc7);

    float carry = 0.f;
#pragma unroll
    for (int e = 0; e < TE; ++e) {
        if (e0 + e < E) {
            carry += acc7[e];
            bool flush = (e == TE - 1) || (e0 + e + 1 >= E) || (s_hi[e + 1] != s_hi[e]);
            if (flush) {
                atomicAdd(&c_acc[(size_t)s_hi[e] * D + j], carry);
                carry = 0.f;
            }
        }
    }
}

// out = relu( GN( relu(GN(agts@agt_w.T + c_acc)) @ lin_w.T ) + agts )
__global__ __launch_bounds__(128) void final_kernel(
    const float* __restrict__ c_acc, const float* __restrict__ agts,
    const float* __restrict__ agt_w,
    const float* __restrict__ norm_g, const float* __restrict__ norm_beta,
    const float* __restrict__ lin_w, const float* __restrict__ lin_g, const float* __restrict__ lin_beta,
    float* __restrict__ out, int n)
{
    __shared__ float xbuf[TE][D];
    __shared__ float red_m[TE], red_r[TE];
    const int j  = threadIdx.x;
    const int r0 = blockIdx.x * TE;

    float res[TE];
#pragma unroll
    for (int e = 0; e < TE; ++e) {
        int r = min(r0 + e, n - 1);
        float v = agts[(size_t)r * D + j];
        res[e] = v;
        xbuf[e][j] = v;
    }
    __syncthreads();

    // base GEMM + scattered edge contributions
    float accA[TE];
#pragma unroll
    for (int e = 0; e < TE; ++e) accA[e] = 0.f;
    mm_acc(&xbuf[0][0], agt_w + (size_t)j * D, accA);
#pragma unroll
    for (int e = 0; e < TE; ++e) {
        int r = min(r0 + e, n - 1);
        accA[e] += c_acc[(size_t)r * D + j];
    }
    __syncthreads();                 // all xbuf reads done

    // GN #1 + relu
#pragma unroll
    for (int e = 0; e < TE; ++e) xbuf[e][j] = accA[e];
    __syncthreads();
    gn_reduce(&xbuf[0][0], red_m, red_r, j);
    __syncthreads();
    {
        float g1 = norm_g[j], b1 = norm_beta[j];
#pragma unroll
        for (int e = 0; e < TE; ++e)
            xbuf[e][j] = fmaxf(fmaf((accA[e] - red_m[e]) * red_r[e], g1, b1), 0.f);
    }
    __syncthreads();

    // lin GEMM
    float accB[TE];
#pragma unroll
    for (int e = 0; e < TE; ++e) accB[e] = 0.f;
    mm_acc(&xbuf[0][0], lin_w + (size_t)j * D, accB);
    __syncthreads();

    // GN #2 + residual + relu
#pragma unroll
    for (int e = 0; e < TE; ++e) xbuf[e][j] = accB[e];
    __syncthreads();
    gn_reduce(&xbuf[0][0], red_m, red_r, j);
    __syncthreads();
    {
        float g2 = lin_g[j], b2 = lin_beta[j];
#pragma unroll
        for (int e = 0; e < TE; ++e) {
            int r = r0 + e;
            if (r < n) {
                float y = fmaf((accB[e] - red_m[e]) * red_r[e], g2, b2);
                out[(size_t)r * D + j] = fmaxf(y + res[e], 0.f);
            }
        }
    }
}

extern "C" void kernel_launch(void* const* d_in, const int* in_sizes, int n_in,
                              void* d_out, int out_size, void* d_ws, size_t ws_size,
                              hipStream_t stream)
{
    const float* agts      = (const float*)d_in[0];
    const float* ctx       = (const float*)d_in[1];
    const float* agt_ctrs  = (const float*)d_in[2];
    const float* ctx_ctrs  = (const float*)d_in[3];
    const float* dist_w1   = (const float*)d_in[4];
    const float* dist_b1   = (const float*)d_in[5];
    const float* dist_w2   = (const float*)d_in[6];
    const float* dist_g    = (const float*)d_in[7];
    const float* dist_beta = (const float*)d_in[8];
    const float* q_w       = (const float*)d_in[9];
    const float* q_g       = (const float*)d_in[10];
    const float* q_beta    = (const float*)d_in[11];
    const float* ctx_w1    = (const float*)d_in[12];
    const float* ctx_g     = (const float*)d_in[13];
    const float* ctx_beta  = (const float*)d_in[14];
    const float* ctx_w2    = (const float*)d_in[15];
    const float* agt_w     = (const float*)d_in[16];
    const float* norm_g    = (const float*)d_in[17];
    const float* norm_beta = (const float*)d_in[18];
    const float* lin_w     = (const float*)d_in[19];
    const float* lin_g     = (const float*)d_in[20];
    const float* lin_beta  = (const float*)d_in[21];
    const int*   hi        = (const int*)d_in[22];
    const int*   wi        = (const int*)d_in[23];

    const int N = in_sizes[0] / D;
    const int E = in_sizes[22];

    float* c_acc = (float*)d_ws;      // N*D fp32 edge-contribution accumulator
    float* out   = (float*)d_out;

    const int n4 = (N * D) / 4;
    zero_kernel<<<(n4 + 255) / 256 < 2048 ? (n4 + 255) / 256 : 2048, 256, 0, stream>>>(
        (float4*)c_acc, n4);

    if (E > 0) {
        const int eb = (E + TE - 1) / TE;
        edge_kernel<<<eb, 128, 0, stream>>>(agts, ctx, agt_ctrs, ctx_ctrs,
                                            dist_w1, dist_b1, dist_w2, dist_g, dist_beta,
                                            q_w, q_g, q_beta, ctx_w1, ctx_g, ctx_beta, ctx_w2,
                                            hi, wi, c_acc, E);
    }
    const int nb = (N + TE - 1) / TE;
    final_kernel<<<nb, 128, 0, stream>>>(c_acc, agts, agt_w,
                                         norm_g, norm_beta,
                                         lin_w, lin_g, lin_beta, out, N);
}

// Round 7
// 2260.059 us; speedup vs baseline: 1.1626x; 1.1626x over previous
//
#include <hip/hip_runtime.h>

#define D 128
#define TE 16
#define TPE 8            // threads per row in GN reduction (128 threads / 16 rows)
#define EPS 1e-5f

typedef __attribute__((ext_vector_type(8))) short short8;
typedef __attribute__((ext_vector_type(4))) float f32x4;

// ---------- bf16 helpers (bit-level, RNE) ----------
__device__ __forceinline__ unsigned short f32_to_bf16(float x) {
    unsigned u = __float_as_uint(x);
    return (unsigned short)((u + 0x7fffu + ((u >> 16) & 1u)) >> 16);
}
__device__ __forceinline__ float bf16_to_f32(unsigned short h) {
    return __uint_as_float(((unsigned)h) << 16);
}
__device__ __forceinline__ void split_bf16(float x, unsigned short& hi, unsigned short& lo) {
    hi = f32_to_bf16(x);
    lo = f32_to_bf16(x - bf16_to_f32(hi));
}

// Swizzled element index into xh/xl [TE][D] bf16: 16B slots XORed by row&15.
__device__ __forceinline__ int swz(int e, int c) {
    return e * D + ((((c >> 3) ^ e) & 15) << 3) + (c & 7);
}

__device__ __forceinline__ f32x4 mfma16(short8 a, short8 b, f32x4 c) {
    return __builtin_amdgcn_mfma_f32_16x16x32_bf16(a, b, c, 0, 0, 0);
}

// ---------- round-3 scalar building blocks (validated) ----------
__device__ __forceinline__ void gn_reduce(const float* buf, float* red_m, float* red_r, int j)
{
    int e = j / TPE;
    int t = j % TPE;
    float s = 0.f, s2 = 0.f;
#pragma unroll
    for (int q = 0; q < D / TPE; ++q) {
        float v = buf[e * D + t * (D / TPE) + q];
        s += v; s2 += v * v;
    }
#pragma unroll
    for (int m = TPE / 2; m > 0; m >>= 1) {
        s  += __shfl_xor(s, m);
        s2 += __shfl_xor(s2, m);
    }
    if (t == 0) {
        float mean = s * (1.f / D);
        float var  = s2 * (1.f / D) - mean * mean;
        red_m[e] = mean;
        red_r[e] = rsqrtf(fmaxf(var, 0.f) + EPS);
    }
}

__device__ __forceinline__ void mm_acc(const float* in, const float* __restrict__ Wrow,
                                       float acc[TE])
{
    const float4* W4 = reinterpret_cast<const float4*>(Wrow);
    for (int k4 = 0; k4 < D / 4; ++k4) {
        float4 w = W4[k4];
#pragma unroll
        for (int e = 0; e < TE; ++e) {
            float4 x = *reinterpret_cast<const float4*>(&in[e * D + 4 * k4]);
            acc[e] = fmaf(w.x, x.x, fmaf(w.y, x.y, fmaf(w.z, x.z, fmaf(w.w, x.w, acc[e]))));
        }
    }
}

__device__ __forceinline__ void mm_gn(const float* in, const float* __restrict__ W,
                                      const float* __restrict__ g, const float* __restrict__ b,
                                      float* out, float* red_m, float* red_r, int j)
{
    float acc[TE];
#pragma unroll
    for (int e = 0; e < TE; ++e) acc[e] = 0.f;
    mm_acc(in, W + (size_t)j * D, acc);
#pragma unroll
    for (int e = 0; e < TE; ++e) out[e * D + j] = acc[e];
    __syncthreads();
    gn_reduce(out, red_m, red_r, j);
    __syncthreads();
    float gj = g[j], bj = b[j];
#pragma unroll
    for (int e = 0; e < TE; ++e)
        out[e * D + j] = fmaxf(fmaf((acc[e] - red_m[e]) * red_r[e], gj, bj), 0.f);
    __syncthreads();
}

__global__ __launch_bounds__(256) void zero_kernel(float4* __restrict__ p, int n4)
{
    int i = blockIdx.x * 256 + threadIdx.x;
    int stride = gridDim.x * 256;
    for (; i < n4; i += stride) p[i] = make_float4(0.f, 0.f, 0.f, 0.f);
}

// ---------- edge kernel: round-3 structure; ONLY the q-branch GEMM is MFMA ----------
__global__ __launch_bounds__(128) void edge_kernel(
    const float* __restrict__ agts, const float* __restrict__ ctx,
    const float* __restrict__ agt_ctrs, const float* __restrict__ ctx_ctrs,
    const float* __restrict__ dist_w1, const float* __restrict__ dist_b1,
    const float* __restrict__ dist_w2, const float* __restrict__ dist_g, const float* __restrict__ dist_beta,
    const float* __restrict__ q_w, const float* __restrict__ q_g, const float* __restrict__ q_beta,
    const float* __restrict__ ctx_w1, const float* __restrict__ ctx_g, const float* __restrict__ ctx_beta,
    const float* __restrict__ ctx_w2,
    const int* __restrict__ hi, const int* __restrict__ wi,
    float* __restrict__ c_acc, int E)
{
    __shared__ float bufA[TE][D];
    __shared__ float bufB[TE][D];
    __shared__ __align__(16) unsigned short xh[TE * D];   // 4KB split-hi (swizzled)
    __shared__ __align__(16) unsigned short xl[TE * D];   // 4KB split-lo (swizzled)
    __shared__ float red_m[TE], red_r[TE];
    __shared__ int   s_hi[TE], s_wi[TE];
    __shared__ float s_dx[TE], s_dy[TE];

    const int j  = threadIdx.x;
    const int e0 = blockIdx.x * TE;

    if (j < TE) {
        int ec = min(e0 + j, E - 1);          // tail: clamp (stores guarded)
        int h = hi[ec], w = wi[ec];
        s_hi[j] = h; s_wi[j] = w;
        s_dx[j] = agt_ctrs[2 * h]     - ctx_ctrs[2 * w];
        s_dy[j] = agt_ctrs[2 * h + 1] - ctx_ctrs[2 * w + 1];
    }
    __syncthreads();

    // P2: bufA = relu(d2 @ dist_w1.T + dist_b1)
    {
        float w0 = dist_w1[2 * j], w1 = dist_w1[2 * j + 1], bb = dist_b1[j];
#pragma unroll
        for (int e = 0; e < TE; ++e)
            bufA[e][j] = fmaxf(fmaf(s_dx[e], w0, fmaf(s_dy[e], w1, bb)), 0.f);
    }
    __syncthreads();

    // P3: bufB = relu(GN(bufA @ dist_w2.T))        [scalar, validated]
    mm_gn(&bufA[0][0], dist_w2, dist_g, dist_beta, &bufB[0][0], red_m, red_r, j);

    // P4: acc6 += bufB @ ctx_w1.T (K-chunk 0)      [scalar, validated]
    float acc6[TE];
#pragma unroll
    for (int e = 0; e < TE; ++e) acc6[e] = 0.f;
    mm_acc(&bufB[0][0], ctx_w1 + (size_t)j * (3 * D), acc6);

    // P5a: stage agts[hi] as SPLIT bf16 into swizzled xh/xl   [MFMA path under test]
    {
        int row = j >> 3, t = j & 7;      // 128 threads -> 16 rows x 8 col-groups
        const float* p = agts + (size_t)s_hi[row] * D + t * 16;
#pragma unroll
        for (int h = 0; h < 2; ++h) {
            union { unsigned short u[8]; short8 v; } H, L;
#pragma unroll
            for (int q = 0; q < 2; ++q) {
                float4 x = *(const float4*)(p + h * 8 + q * 4);
                split_bf16(x.x, H.u[q*4+0], L.u[q*4+0]);
                split_bf16(x.y, H.u[q*4+1], L.u[q*4+1]);
                split_bf16(x.z, H.u[q*4+2], L.u[q*4+2]);
                split_bf16(x.w, H.u[q*4+3], L.u[q*4+3]);
            }
            int idx = swz(row, t * 16 + h * 8);
            *(short8*)&xh[idx] = H.v;
            *(short8*)&xl[idx] = L.v;
        }
    }
    __syncthreads();   // orders P4's bufB reads AND P5a's xh/xl writes

    // P6: q-branch GEMM via MFMA: bufB[e][jj] = (agts[hi] @ q_w.T)[e][jj]
    // 2 waves; wave w owns output cols [w*64, w*64+64). A = split X (LDS),
    // B = q_w rows split IN REGISTER from fp32 global (no prep kernel).
    {
        const int lane = j & 63, w = j >> 6;
        const int lrow = lane & 15, lgrp = lane >> 4;
        f32x4 accq[4];
#pragma unroll
        for (int ct = 0; ct < 4; ++ct) accq[ct] = f32x4{0.f, 0.f, 0.f, 0.f};
#pragma unroll
        for (int ks = 0; ks < 4; ++ks) {
            const int c0 = ks * 32 + lgrp * 8;
            int idx = swz(lrow, c0);
            short8 ah = *(const short8*)&xh[idx];
            short8 al = *(const short8*)&xl[idx];
#pragma unroll
            for (int ct = 0; ct < 4; ++ct) {
                int jj = w * 64 + ct * 16 + lrow;
                const float* wp = q_w + (size_t)jj * D + c0;
                float4 f0 = *(const float4*)(wp);
                float4 f1 = *(const float4*)(wp + 4);
                union { unsigned short u[8]; short8 v; } BH, BL;
                split_bf16(f0.x, BH.u[0], BL.u[0]);
                split_bf16(f0.y, BH.u[1], BL.u[1]);
                split_bf16(f0.z, BH.u[2], BL.u[2]);
                split_bf16(f0.w, BH.u[3], BL.u[3]);
                split_bf16(f1.x, BH.u[4], BL.u[4]);
                split_bf16(f1.y, BH.u[5], BL.u[5]);
                split_bf16(f1.z, BH.u[6], BL.u[6]);
                split_bf16(f1.w, BH.u[7], BL.u[7]);
                accq[ct] = mfma16(ah, BH.v, accq[ct]);
                accq[ct] = mfma16(ah, BL.v, accq[ct]);
                accq[ct] = mfma16(al, BH.v, accq[ct]);
            }
        }
        // C-frag (m89: row=(lane>>4)*4+reg, col=lane&15) -> bufB[e][jj]
#pragma unroll
        for (int ct = 0; ct < 4; ++ct) {
            int jj = w * 64 + ct * 16 + (lane & 15);
#pragma unroll
            for (int r = 0; r < 4; ++r)
                bufB[lgrp * 4 + r][jj] = accq[ct][r];
        }
    }
    __syncthreads();

    // GN + relu on bufB (q_g/q_beta), in place (replicates mm_gn's tail)
    gn_reduce(&bufB[0][0], red_m, red_r, j);
    __syncthreads();
    {
        float gj = q_g[j], bj = q_beta[j];
#pragma unroll
        for (int e = 0; e < TE; ++e)
            bufB[e][j] = fmaxf(fmaf((bufB[e][j] - red_m[e]) * red_r[e], gj, bj), 0.f);
    }
    __syncthreads();

    // P7: acc6 += bufB @ ctx_w1.T (K-chunk 1)      [scalar, validated]
    mm_acc(&bufB[0][0], ctx_w1 + (size_t)j * (3 * D) + D, acc6);
    __syncthreads();   // all bufB reads done before overwrite

    // P8: bufB = ctx[wi] rows
#pragma unroll
    for (int e = 0; e < TE; ++e) bufB[e][j] = ctx[(size_t)s_wi[e] * D + j];
    __syncthreads();

    // P9: acc6 += bufB @ ctx_w1.T (K-chunk 2)
    mm_acc(&bufB[0][0], ctx_w1 + (size_t)j * (3 * D) + 2 * D, acc6);

    // P10: bufA = relu(GN(acc6))
#pragma unroll
    for (int e = 0; e < TE; ++e) bufA[e][j] = acc6[e];
    __syncthreads();
    gn_reduce(&bufA[0][0], red_m, red_r, j);
    __syncthreads();
    {
        float gj = ctx_g[j], bj = ctx_beta[j];
#pragma unroll
        for (int e = 0; e < TE; ++e)
            bufA[e][j] = fmaxf(fmaf((acc6[e] - red_m[e]) * red_r[e], gj, bj), 0.f);
    }
    __syncthreads();

    // P11: acc7 = bufA @ ctx_w2.T ; run-merged scatter-add (hi sorted)
    float acc7[TE];
#pragma unroll
    for (int e = 0; e < TE; ++e) acc7[e] = 0.f;
    mm_acc(&bufA[0][0], ctx_w2 + (size_t)j * D, acc7);

    float carry = 0.f;
#pragma unroll
    for (int e = 0; e < TE; ++e) {
        if (e0 + e < E) {
            carry += acc7[e];
            bool flush = (e == TE - 1) || (e0 + e + 1 >= E) || (s_hi[e + 1] != s_hi[e]);
            if (flush) {
                atomicAdd(&c_acc[(size_t)s_hi[e] * D + j], carry);
                carry = 0.f;
            }
        }
    }
}

// ---------- final fp32 kernel (unchanged, validated round 3) ----------
__global__ __launch_bounds__(128) void final_kernel(
    const float* __restrict__ c_acc, const float* __restrict__ agts,
    const float* __restrict__ agt_w,
    const float* __restrict__ norm_g, const float* __restrict__ norm_beta,
    const float* __restrict__ lin_w, const float* __restrict__ lin_g, const float* __restrict__ lin_beta,
    float* __restrict__ out, int n)
{
    __shared__ float xbuf[TE][D];
    __shared__ float red_m[TE], red_r[TE];
    const int j  = threadIdx.x;
    const int r0 = blockIdx.x * TE;

    float res[TE];
#pragma unroll
    for (int e = 0; e < TE; ++e) {
        int r = min(r0 + e, n - 1);
        float v = agts[(size_t)r * D + j];
        res[e] = v;
        xbuf[e][j] = v;
    }
    __syncthreads();

    float accA[TE];
#pragma unroll
    for (int e = 0; e < TE; ++e) accA[e] = 0.f;
    mm_acc(&xbuf[0][0], agt_w + (size_t)j * D, accA);
#pragma unroll
    for (int e = 0; e < TE; ++e) {
        int r = min(r0 + e, n - 1);
        accA[e] += c_acc[(size_t)r * D + j];
    }
    __syncthreads();

#pragma unroll
    for (int e = 0; e < TE; ++e) xbuf[e][j] = accA[e];
    __syncthreads();
    gn_reduce(&xbuf[0][0], red_m, red_r, j);
    __syncthreads();
    {
        float g1 = norm_g[j], b1 = norm_beta[j];
#pragma unroll
        for (int e = 0; e < TE; ++e)
            xbuf[e][j] = fmaxf(fmaf((accA[e] - red_m[e]) * red_r[e], g1, b1), 0.f);
    }
    __syncthreads();

    float accB[TE];
#pragma unroll
    for (int e = 0; e < TE; ++e) accB[e] = 0.f;
    mm_acc(&xbuf[0][0], lin_w + (size_t)j * D, accB);
    __syncthreads();

#pragma unroll
    for (int e = 0; e < TE; ++e) xbuf[e][j] = accB[e];
    __syncthreads();
    gn_reduce(&xbuf[0][0], red_m, red_r, j);
    __syncthreads();
    {
        float g2 = lin_g[j], b2 = lin_beta[j];
#pragma unroll
        for (int e = 0; e < TE; ++e) {
            int r = r0 + e;
            if (r < n) {
                float y = fmaf((accB[e] - red_m[e]) * red_r[e], g2, b2);
                out[(size_t)r * D + j] = fmaxf(y + res[e], 0.f);
            }
        }
    }
}

extern "C" void kernel_launch(void* const* d_in, const int* in_sizes, int n_in,
                              void* d_out, int out_size, void* d_ws, size_t ws_size,
                              hipStream_t stream)
{
    const float* agts      = (const float*)d_in[0];
    const float* ctx       = (const float*)d_in[1];
    const float* agt_ctrs  = (const float*)d_in[2];
    const float* ctx_ctrs  = (const float*)d_in[3];
    const float* dist_w1   = (const float*)d_in[4];
    const float* dist_b1   = (const float*)d_in[5];
    const float* dist_w2   = (const float*)d_in[6];
    const float* dist_g    = (const float*)d_in[7];
    const float* dist_beta = (const float*)d_in[8];
    const float* q_w       = (const float*)d_in[9];
    const float* q_g       = (const float*)d_in[10];
    const float* q_beta    = (const float*)d_in[11];
    const float* ctx_w1    = (const float*)d_in[12];
    const float* ctx_g     = (const float*)d_in[13];
    const float* ctx_beta  = (const float*)d_in[14];
    const float* ctx_w2    = (const float*)d_in[15];
    const float* agt_w     = (const float*)d_in[16];
    const float* norm_g    = (const float*)d_in[17];
    const float* norm_beta = (const float*)d_in[18];
    const float* lin_w     = (const float*)d_in[19];
    const float* lin_g     = (const float*)d_in[20];
    const float* lin_beta  = (const float*)d_in[21];
    const int*   hi        = (const int*)d_in[22];
    const int*   wi        = (const int*)d_in[23];

    const int N = in_sizes[0] / D;
    const int E = in_sizes[22];

    float* c_acc = (float*)d_ws;      // N*D fp32 (round-3-validated placement)
    float* out   = (float*)d_out;

    const int n4 = (N * D) / 4;
    int zb = (n4 + 255) / 256; if (zb > 2048) zb = 2048;
    zero_kernel<<<zb, 256, 0, stream>>>((float4*)c_acc, n4);

    if (E > 0) {
        const int eb = (E + TE - 1) / TE;
        edge_kernel<<<eb, 128, 0, stream>>>(agts, ctx, agt_ctrs, ctx_ctrs,
                                            dist_w1, dist_b1, dist_w2, dist_g, dist_beta,
                                            q_w, q_g, q_beta, ctx_w1, ctx_g, ctx_beta, ctx_w2,
                                            hi, wi, c_acc, E);
    }
    const int nb = (N + TE - 1) / TE;
    final_kernel<<<nb, 128, 0, stream>>>(c_acc, agts, agt_w,
                                         norm_g, norm_beta,
                                         lin_w, lin_g, lin_beta, out, N);
}